// Round 11
// baseline (98.337 us; speedup 1.0000x reference)
//
#include <hip/hip_runtime.h>
#include <hip/hip_bf16.h>

// Problem constants
#define NB    8      // batch
#define NG    64     // c_inp groups (g)
#define NCI   16     // conv in channels (ci)
#define NC0   16     // conv out channels (c0)
#define NJ    64     // c_out (j)
#define IH    64
#define IW    64
#define OH    62
#define OW    62
#define IPIX  4096   // 64*64
#define OPIX  3844   // 62*62

typedef __attribute__((ext_vector_type(8))) short  short8;
typedef __attribute__((ext_vector_type(4))) short  short4v;
typedef __attribute__((ext_vector_type(4))) float  float4v;

__device__ __forceinline__ unsigned short f2bf(float f) {
    unsigned int u = __builtin_bit_cast(unsigned int, f);
    unsigned int r = (u + 0x7fffu + ((u >> 16) & 1u)) >> 16;
    return (unsigned short)r;
}

// ---------------------------------------------------------------------------
// prep: blocks 0..7 build Wm fragments (bf16) (jt = bi>>1, kh = bi&1)
//       block 8 builds conv K-fragments kb (K padded to 160 contraction, bf16)
// Fragment convention (16x16x32 bf16): free index = lane&15, k = (lane>>4)*8+i.
// ---------------------------------------------------------------------------
__global__ __launch_bounds__(64) void prep_kernel(const float* __restrict__ K,
                                                  const float* __restrict__ c0_,
                                                  const float* __restrict__ c1_,
                                                  const float* __restrict__ c2_,
                                                  unsigned short* __restrict__ wmb,
                                                  unsigned short* __restrict__ kb) {
    int bi = blockIdx.x;
    int l  = threadIdx.x;
    if (bi < 8) {
        int jt = bi >> 1, kh = bi & 1;
        int j = jt * 16 + (l & 15);
        int j1 = j >> 4, j2 = (j >> 2) & 3, j3 = j & 3;
        for (int i = 0; i < 8; ++i) {
            int g = kh * 32 + (l >> 4) * 8 + i;
            int i1 = g >> 4, i2 = (g >> 2) & 3, i3 = g & 3;
            float s = 0.f;
            #pragma unroll
            for (int r1 = 0; r1 < 8; ++r1) {
                float a = c0_[(i1 * 4 + j1) * 8 + r1];
                float t = 0.f;
                #pragma unroll
                for (int r2 = 0; r2 < 8; ++r2) {
                    t += c1_[((r1 * 4 + i2) * 4 + j2) * 8 + r2] *
                         c2_[(r2 * 4 + i3) * 4 + j3];
                }
                s += a * t;
            }
            wmb[(bi * 64 + l) * 8 + i] = f2bf(s);
        }
    } else {
        int c0i = l & 15, q = l >> 4;
        for (int f = 0; f < 5; ++f) {
            int tap = f * 2 + (q >> 1);  // 0..9; 9 = zero pad
            for (int i = 0; i < 8; ++i) {
                int ci = (q & 1) * 8 + i;
                float v = (tap < 9) ? K[(c0i * 16 + ci) * 9 + tap] : 0.f;
                kb[(f * 64 + l) * 8 + i] = f2bf(v);
            }
        }
    }
}

// ---------------------------------------------------------------------------
// conv_roll: FIRST stage, rolling-window software pipeline (R11).
// y[b][g*16+c0][yo*64+xo] (bf16) = sum_{ci,tap} K[c0,ci,tap]*x[b,g*16+ci,..]
//
// R10 post-mortem: conv duration fits A + B/(memory concurrency per CU);
// pattern & pipelining-at-fixed-concurrency are second order. R11 = the
// untested matrix cell: pipelining AND high occupancy. Ring 16 -> 12 slots
// (slot = row % 12; live set at iter it = rows 4it..4it+11, exactly 12) ->
// LDS 31.7 KB -> 5 blocks/CU (launch_bounds(256,5)), 2.5x R10's in-flight
// memory. Per iteration: issue next chunk's 4 loads -> compute 4 rows ->
// cvt+ring-write -> barrier. Staging streams, fragment reads, f2bf points
// unchanged vs R10 -> bit-identical numerics.
// grid = 8*64 = 512 blocks of 256 (4 waves).
// ---------------------------------------------------------------------------
#define PXS   20         // ushorts per px slot (40 B; slots 16..19 = pad)
#define SLOTU 1320       // 66 * PXS ushorts per row-slot
#define NSLOT 12

__global__ __launch_bounds__(256, 5) void conv_roll_kernel(const float* __restrict__ x,
                                                           const unsigned short* __restrict__ kb,
                                                           unsigned short* __restrict__ y) {
    __shared__ __align__(16) unsigned short xl[NSLOT * SLOTU];  // 31680 B
    int t = threadIdx.x, lane = t & 63, wv = t >> 6;
    int g = blockIdx.x & 63, b = blockIdx.x >> 6;
    int ln = lane & 15, quad = lane >> 4;
    int sub = lane >> 4;             // staging: row within 4-row chunk
    int px4 = (lane & 15) * 4;       // staging: px quad base

    const float* xg = x + (size_t)(b * 1024 + g * 16) * IPIX;
    // staging stream base: ci = wv*4 + j, lane covers (row sub, px quad)
    const float* cbase = xg + (size_t)(wv * 4) * IPIX + sub * 64 + px4;

    // conv fragments + tap geometry
    short8 kf[5]; int dyf[5], dxo[5];
    #pragma unroll
    for (int f = 0; f < 5; ++f) {
        kf[f] = *(const short8*)(kb + (f * 64 + lane) * 8);
        int tap = f * 2 + (quad >> 1);
        if (tap > 8) tap = 8;        // pad chunk: kb is zero there
        dyf[f] = tap / 3;
        dxo[f] = (tap % 3) * PXS;
    }
    int h8 = (quad & 1) * 8;

    // zero-pad px 64,65 in all ring slots (stay zero forever)
    for (int e = t; e < NSLOT * 32; e += 256) {
        int s = e >> 5, rem = e & 31;          // px(2) x ci(16)
        xl[s * SLOTU + (64 + (rem >> 4)) * PXS + (rem & 15)] = 0;
    }

    // ---- prologue: stage input rows 0..7 (slots 0..7) ----
    #pragma unroll
    for (int c = 0; c < 2; ++c) {
        int r0 = c * 4;
        const float* a = cbase + (size_t)r0 * 64;
        float4v q0 = *(const float4v*)(a);              // ci wv*4+0
        float4v q1 = *(const float4v*)(a + IPIX);       // ci wv*4+1
        float4v q2 = *(const float4v*)(a + 2 * IPIX);   // ci wv*4+2
        float4v q3 = *(const float4v*)(a + 3 * IPIX);   // ci wv*4+3
        unsigned short* dst = xl + ((r0 + sub) % NSLOT) * SLOTU + px4 * PXS + wv * 4;
        #pragma unroll
        for (int p = 0; p < 4; ++p) {
            short4v u;
            u[0] = (short)f2bf(q0[p]); u[1] = (short)f2bf(q1[p]);
            u[2] = (short)f2bf(q2[p]); u[3] = (short)f2bf(q3[p]);
            *(short4v*)(dst + p * PXS) = u;
        }
    }
    __syncthreads();

    // ---- main loop: 16 iterations of 4 output rows ----
    for (int it = 0; it < 16; ++it) {
        bool ld = (it <= 13);                  // rows 8..63 loaded by it=13
        int r0 = it * 4 + 8;
        float4v q0, q1, q2, q3;
        if (ld) {                              // issue loads EARLY (prefetch)
            const float* a = cbase + (size_t)r0 * 64;
            q0 = *(const float4v*)(a);
            q1 = *(const float4v*)(a + IPIX);
            q2 = *(const float4v*)(a + 2 * IPIX);
            q3 = *(const float4v*)(a + 3 * IPIX);
        }

        int yo = it * 4 + wv;                  // this wave's output row
        if (yo < OH) {
            int sb[5];
            #pragma unroll
            for (int f = 0; f < 5; ++f)
                sb[f] = ((yo + dyf[f]) % NSLOT) * SLOTU;
            #pragma unroll
            for (int xt = 0; xt < 4; ++xt) {
                int x0 = xt * 16;
                int pxoff = (x0 + ln) * PXS + h8;
                float4v acc = {0.f, 0.f, 0.f, 0.f};
                #pragma unroll
                for (int f = 0; f < 5; ++f) {
                    const unsigned short* p = xl + sb[f] + pxoff + dxo[f];
                    short4v lo = *(const short4v*)(p);
                    short4v hi = *(const short4v*)(p + 4);
                    short8 a = __builtin_shufflevector(lo, hi, 0, 1, 2, 3, 4, 5, 6, 7);
                    acc = __builtin_amdgcn_mfma_f32_16x16x32_bf16(a, kf[f], acc, 0, 0, 0);
                }
                // D: col = ln = c0, rows = px = x0 + quad*4 + r
                unsigned short* yp = y + ((size_t)(b * 1024 + g * 16 + ln) * 4096
                                          + yo * 64 + x0 + quad * 4);
                short4v o;
                o[0] = (short)f2bf(acc[0]); o[1] = (short)f2bf(acc[1]);
                o[2] = (short)f2bf(acc[2]); o[3] = (short)f2bf(acc[3]);
                *(short4v*)yp = o;
            }
        }

        if (ld) {                              // cvt + ring write (late)
            unsigned short* dst = xl + ((r0 + sub) % NSLOT) * SLOTU + px4 * PXS + wv * 4;
            #pragma unroll
            for (int p = 0; p < 4; ++p) {
                short4v u;
                u[0] = (short)f2bf(q0[p]); u[1] = (short)f2bf(q1[p]);
                u[2] = (short)f2bf(q2[p]); u[3] = (short)f2bf(q3[p]);
                *(short4v*)(dst + p * PXS) = u;
            }
        }
        __syncthreads();
    }
}

// ---------------------------------------------------------------------------
// mix3: SECOND stage. out[b][c0][pix][j] = bias[j] + sum_g y[b,(g,c0),pix]*Wm[g,j]
// Full-128-B-line bf16 gather on L3-resident y; at its write-roofline (~20us).
// grid = 8b * 62 rows = 496 blocks of 512.
// ---------------------------------------------------------------------------
__global__ __launch_bounds__(512, 2) void mix3_kernel(const unsigned short* __restrict__ y,
                                                      const unsigned short* __restrict__ wmb,
                                                      const float* __restrict__ bias,
                                                      float* __restrict__ out) {
    __shared__ __align__(16) unsigned short yl[64 * 1024];  // 128 KB
    int t    = threadIdx.x;
    int bi   = blockIdx.x;
    int prow = bi % OH;
    int b    = bi / OH;

    // ---- stage y row-tile (64 px x 1024 ch) -> LDS, swizzled ----
    {
        int pq = t & 7, grp = t >> 3;                 // 8 px-octets x 64 groups
        const unsigned short* yb = y + ((size_t)b * 1024 * 4096) + prow * 64 + pq * 8;
        #pragma unroll
        for (int it = 0; it < 4; ++it) {
            int qd = it * 64 + grp;                   // 0..255: gq 0..15, c0 0..15
            int gq = qd & 15, c0 = qd >> 4;
            const unsigned short* yp = yb + (size_t)(gq * 4 * 16 + c0) * 4096;
            short8 v0 = *(const short8*)(yp);
            short8 v1 = *(const short8*)(yp + 16 * 4096);
            short8 v2 = *(const short8*)(yp + 32 * 4096);
            short8 v3 = *(const short8*)(yp + 48 * 4096);
            int chunk = gq >> 1;
            int gof   = (gq & 1) * 4;                 // g&7 base within chunk
            #pragma unroll
            for (int pp = 0; pp < 8; ++pp) {
                int px = pq * 8 + pp;
                int csw = chunk ^ (c0 & 7) ^ (pq & 7);
                short4v u;
                u[0] = v0[pp]; u[1] = v1[pp]; u[2] = v2[pp]; u[3] = v3[pp];
                *(short4v*)(yl + px * 1024 + c0 * 64 + csw * 8 + gof) = u;
            }
        }
    }
    __syncthreads();

    // ---- compute: 8 waves x 8 px ----
    int lane = t & 63, wv = t >> 6;
    int ln = lane & 15, quad = lane >> 4;

    short8 bf[8];
    #pragma unroll
    for (int q8 = 0; q8 < 8; ++q8)
        bf[q8] = *(const short8*)(wmb + (q8 * 64 + lane) * 8);  // [jt*2+kh]

    float4v bv[4];
    #pragma unroll
    for (int jt = 0; jt < 4; ++jt)
        bv[jt] = *(const float4v*)(bias + jt * 16 + quad * 4);

    for (int kk = 0; kk < 8; ++kk) {
        int pl = wv * 8 + kk;                         // px in tile = xout
        const unsigned short* arow = yl + pl * 1024 + ln * 64;
        int sx = (ln & 7) ^ ((pl >> 3) & 7);
        short8 a0 = *(const short8*)(arow + (((0 + quad) ^ sx) * 8));
        short8 a1 = *(const short8*)(arow + (((4 + quad) ^ sx) * 8));
        if (pl < OW) {
            float* ob = out + (((size_t)(b * 16 + ln) * OPIX) + prow * OW + pl) * NJ
                        + quad * 4;
            #pragma unroll
            for (int jt = 0; jt < 4; ++jt) {
                float4v acc = bv[jt];
                acc = __builtin_amdgcn_mfma_f32_16x16x32_bf16(bf[jt * 2 + 0], a0, acc, 0, 0, 0);
                acc = __builtin_amdgcn_mfma_f32_16x16x32_bf16(bf[jt * 2 + 1], a1, acc, 0, 0, 0);
                *(float4v*)(ob + jt * 16) = acc;
            }
        }
    }
}

// ---------------------------------------------------------------------------
// Fallback path (small ws): round-1 kernels, fp32 throughout.
// ---------------------------------------------------------------------------
__global__ __launch_bounds__(64) void wm_kernel(const float* __restrict__ core0,
                                                const float* __restrict__ core1,
                                                const float* __restrict__ core2,
                                                float* __restrict__ Wm) {
    int g = threadIdx.x;
    int i1 = g >> 4, i2 = (g >> 2) & 3, i3 = g & 3;
    for (int j = 0; j < NJ; ++j) {
        int j1 = j >> 4, j2 = (j >> 2) & 3, j3 = j & 3;
        float s = 0.f;
        #pragma unroll
        for (int r1 = 0; r1 < 8; ++r1) {
            float a = core0[(i1 * 4 + j1) * 8 + r1];
            float t = 0.f;
            #pragma unroll
            for (int r2 = 0; r2 < 8; ++r2) {
                t += core1[((r1 * 4 + i2) * 4 + j2) * 8 + r2] *
                     core2[(r2 * 4 + i3) * 4 + j3];
            }
            s += a * t;
        }
        Wm[g * NJ + j] = s;
    }
}

__global__ __launch_bounds__(256) void fused_fallback(const float* __restrict__ x,
                                                      const float* __restrict__ K,
                                                      const float* __restrict__ Wm,
                                                      const float* __restrict__ bias,
                                                      float* __restrict__ out) {
    __shared__ float wlds[NG * NJ];
    __shared__ float klds[NCI * 9];
    int blk  = blockIdx.x;
    int pblk = blk & 15;
    int c0   = (blk >> 4) & 15;
    int b    = blk >> 8;
    for (int i = threadIdx.x; i < NG * NJ; i += 256) wlds[i] = Wm[i];
    for (int i = threadIdx.x; i < NCI * 9; i += 256) klds[i] = K[c0 * NCI * 9 + i];
    __syncthreads();

    int pix = pblk * 256 + threadIdx.x;
    if (pix >= OPIX) return;
    int yy = pix / OW;
    int xx = pix % OW;

    float acc[NJ];
    #pragma unroll
    for (int j = 0; j < NJ; ++j) acc[j] = 0.f;

    for (int g = 0; g < NG; ++g) {
        float c = 0.f;
        const float* xb = x + ((size_t)(b * NG + g) * NCI) * IPIX;
        for (int ci = 0; ci < NCI; ++ci) {
            #pragma unroll
            for (int dy = 0; dy < 3; ++dy) {
                #pragma unroll
                for (int dx = 0; dx < 3; ++dx) {
                    c += xb[ci * IPIX + (yy + dy) * IW + (xx + dx)] *
                         klds[ci * 9 + dy * 3 + dx];
                }
            }
        }
        const float4* wp = (const float4*)&wlds[g * NJ];
        #pragma unroll
        for (int j4 = 0; j4 < 16; ++j4) {
            float4 w = wp[j4];
            acc[j4 * 4 + 0] += w.x * c;
            acc[j4 * 4 + 1] += w.y * c;
            acc[j4 * 4 + 2] += w.z * c;
            acc[j4 * 4 + 3] += w.w * c;
        }
    }
    #pragma unroll
    for (int j = 0; j < NJ; ++j) {
        out[(((size_t)(b * NC0 + c0) * OPIX) + pix) * NJ + j] = acc[j] + bias[j];
    }
}

extern "C" void kernel_launch(void* const* d_in, const int* in_sizes, int n_in,
                              void* d_out, int out_size, void* d_ws, size_t ws_size,
                              hipStream_t stream) {
    const float* x     = (const float*)d_in[0];
    const float* K     = (const float*)d_in[1];
    const float* core0 = (const float*)d_in[2];
    const float* core1 = (const float*)d_in[3];
    const float* core2 = (const float*)d_in[4];
    const float* bias  = (const float*)d_in[5];
    float* out = (float*)d_out;

    const size_t z_off   = 16384;
    const size_t z_bytes = (size_t)NB * 1024 * 4096 * sizeof(unsigned short);  // 67.1 MB

    if (ws_size >= z_off + z_bytes + 256) {
        unsigned short* wmb = (unsigned short*)d_ws;                    // 8 KB
        unsigned short* kb  = (unsigned short*)((char*)d_ws + 8192);    // 5 KB
        unsigned short* y   = (unsigned short*)((char*)d_ws + z_off);
        prep_kernel<<<9, 64, 0, stream>>>(K, core0, core1, core2, wmb, kb);
        conv_roll_kernel<<<NB * NG, 256, 0, stream>>>(x, kb, y);
        mix3_kernel<<<NB * OH, 512, 0, stream>>>(y, wmb, bias, out);
    } else {
        float* Wm = (float*)d_ws;
        wm_kernel<<<1, 64, 0, stream>>>(core0, core1, core2, Wm);
        fused_fallback<<<NB * NC0 * 16, 256, 0, stream>>>(x, K, Wm, bias, out);
    }
}

// Round 12
// 97.818 us; speedup vs baseline: 1.0053x; 1.0053x over previous
//
#include <hip/hip_runtime.h>
#include <hip/hip_bf16.h>

// Problem constants
#define NB    8      // batch
#define NG    64     // c_inp groups (g)
#define NCI   16     // conv in channels (ci)
#define NC0   16     // conv out channels (c0)
#define NJ    64     // c_out (j)
#define IH    64
#define IW    64
#define OH    62
#define OW    62
#define IPIX  4096   // 64*64
#define OPIX  3844   // 62*62

typedef __attribute__((ext_vector_type(8))) short  short8;
typedef __attribute__((ext_vector_type(4))) short  short4v;
typedef __attribute__((ext_vector_type(4))) float  float4v;

__device__ __forceinline__ unsigned short f2bf(float f) {
    unsigned int u = __builtin_bit_cast(unsigned int, f);
    unsigned int r = (u + 0x7fffu + ((u >> 16) & 1u)) >> 16;
    return (unsigned short)r;
}

// ---------------------------------------------------------------------------
// prep: blocks 0..7 build Wm fragments (bf16) (jt = bi>>1, kh = bi&1)
//       block 8 builds conv K-fragments kb (K padded to 160 contraction, bf16)
// Fragment convention (16x16x32 bf16): free index = lane&15, k = (lane>>4)*8+i.
// ---------------------------------------------------------------------------
__global__ __launch_bounds__(64) void prep_kernel(const float* __restrict__ K,
                                                  const float* __restrict__ c0_,
                                                  const float* __restrict__ c1_,
                                                  const float* __restrict__ c2_,
                                                  unsigned short* __restrict__ wmb,
                                                  unsigned short* __restrict__ kb) {
    int bi = blockIdx.x;
    int l  = threadIdx.x;
    if (bi < 8) {
        int jt = bi >> 1, kh = bi & 1;
        int j = jt * 16 + (l & 15);
        int j1 = j >> 4, j2 = (j >> 2) & 3, j3 = j & 3;
        for (int i = 0; i < 8; ++i) {
            int g = kh * 32 + (l >> 4) * 8 + i;
            int i1 = g >> 4, i2 = (g >> 2) & 3, i3 = g & 3;
            float s = 0.f;
            #pragma unroll
            for (int r1 = 0; r1 < 8; ++r1) {
                float a = c0_[(i1 * 4 + j1) * 8 + r1];
                float t = 0.f;
                #pragma unroll
                for (int r2 = 0; r2 < 8; ++r2) {
                    t += c1_[((r1 * 4 + i2) * 4 + j2) * 8 + r2] *
                         c2_[(r2 * 4 + i3) * 4 + j3];
                }
                s += a * t;
            }
            wmb[(bi * 64 + l) * 8 + i] = f2bf(s);
        }
    } else {
        int c0i = l & 15, q = l >> 4;
        for (int f = 0; f < 5; ++f) {
            int tap = f * 2 + (q >> 1);  // 0..9; 9 = zero pad
            for (int i = 0; i < 8; ++i) {
                int ci = (q & 1) * 8 + i;
                float v = (tap < 9) ? K[(c0i * 16 + ci) * 9 + tap] : 0.f;
                kb[(f * 64 + l) * 8 + i] = f2bf(v);
            }
        }
    }
}

// ---------------------------------------------------------------------------
// conv_roll: FIRST stage, rolling-window pipeline + REAL concurrency (R12).
// y[b][g*16+c0][yo*64+xo] (bf16) = sum_{ci,tap} K[c0,ci,tap]*x[b,g*16+ci,..]
//
// R11 post-mortem: R11 was a no-op -- grid was 512 (=2 blocks/CU), so the
// occupancy bound never bound anything. R12 finally tests pipelining AND
// high concurrency together: each (b,g) is split into 4 row-bands of 16
// (grid 2048 = 8 needed/CU, 5 resident by 31.7 KB LDS cap), rolling 12-slot
// ring unchanged. Per iteration: issue next chunk's 4 loads -> compute 4
// rows -> cvt+ring-write -> barrier. Slot = (absolute row) % 12; liveness:
// reads [4it,4it+5], writes [4it+8,4it+11] -- mod-12 disjoint. Overrun rows
// (>63) clamp and land only in retired slots. Halo cost 1.125x (151 MB).
// Staging streams, fragment reads, f2bf points unchanged -> identical
// numerics. grid = 8*64*4 = 2048 blocks of 256 (4 waves).
// ---------------------------------------------------------------------------
#define PXS   20         // ushorts per px slot (40 B; slots 16..19 = pad)
#define SLOTU 1320       // 66 * PXS ushorts per row-slot
#define NSLOT 12

__global__ __launch_bounds__(256, 5) void conv_roll_kernel(const float* __restrict__ x,
                                                           const unsigned short* __restrict__ kb,
                                                           unsigned short* __restrict__ y) {
    __shared__ __align__(16) unsigned short xl[NSLOT * SLOTU];  // 31680 B
    int t = threadIdx.x, lane = t & 63, wv = t >> 6;
    int split = blockIdx.x & 3;
    int g = (blockIdx.x >> 2) & 63;
    int b = blockIdx.x >> 8;
    int y0 = split * 16;
    int ln = lane & 15, quad = lane >> 4;
    int sub = lane >> 4;             // staging: row within 4-row chunk
    int px4 = (lane & 15) * 4;       // staging: px quad base

    const float* xg = x + (size_t)(b * 1024 + g * 16) * IPIX;
    const float* cch = xg + (size_t)(wv * 4) * IPIX + px4;   // this wave's ci-quad

    // conv fragments + tap geometry
    short8 kf[5]; int dyf[5], dxo[5];
    #pragma unroll
    for (int f = 0; f < 5; ++f) {
        kf[f] = *(const short8*)(kb + (f * 64 + lane) * 8);
        int tap = f * 2 + (quad >> 1);
        if (tap > 8) tap = 8;        // pad chunk: kb is zero there
        dyf[f] = tap / 3;
        dxo[f] = (tap % 3) * PXS;
    }
    int h8 = (quad & 1) * 8;

    // zero-pad px 64,65 in all ring slots (stay zero forever)
    for (int e = t; e < NSLOT * 32; e += 256) {
        int s = e >> 5, rem = e & 31;          // px(2) x ci(16)
        xl[s * SLOTU + (64 + (rem >> 4)) * PXS + (rem & 15)] = 0;
    }

    // ---- prologue: stage input rows y0..y0+7 ----
    #pragma unroll
    for (int c = 0; c < 2; ++c) {
        int r0 = y0 + c * 4;
        int rr = r0 + sub; if (rr > 63) rr = 63;
        const float* a = cch + (size_t)rr * 64;
        float4v q0 = *(const float4v*)(a);              // ci wv*4+0
        float4v q1 = *(const float4v*)(a + IPIX);       // ci wv*4+1
        float4v q2 = *(const float4v*)(a + 2 * IPIX);   // ci wv*4+2
        float4v q3 = *(const float4v*)(a + 3 * IPIX);   // ci wv*4+3
        unsigned short* dst = xl + ((r0 + sub) % NSLOT) * SLOTU + px4 * PXS + wv * 4;
        #pragma unroll
        for (int p = 0; p < 4; ++p) {
            short4v u;
            u[0] = (short)f2bf(q0[p]); u[1] = (short)f2bf(q1[p]);
            u[2] = (short)f2bf(q2[p]); u[3] = (short)f2bf(q3[p]);
            *(short4v*)(dst + p * PXS) = u;
        }
    }
    __syncthreads();

    // ---- main loop: 4 iterations of 4 output rows ----
    for (int it = 0; it < 4; ++it) {
        bool ld = (it <= 2);                   // staged rows y0..y0+19 by it=2
        int r0 = y0 + it * 4 + 8;
        float4v q0, q1, q2, q3;
        if (ld) {                              // issue loads EARLY (prefetch)
            int rr = r0 + sub; if (rr > 63) rr = 63;
            const float* a = cch + (size_t)rr * 64;
            q0 = *(const float4v*)(a);
            q1 = *(const float4v*)(a + IPIX);
            q2 = *(const float4v*)(a + 2 * IPIX);
            q3 = *(const float4v*)(a + 3 * IPIX);
        }

        int yo = y0 + it * 4 + wv;             // this wave's output row
        if (yo < OH) {
            int sb[5];
            #pragma unroll
            for (int f = 0; f < 5; ++f)
                sb[f] = ((yo + dyf[f]) % NSLOT) * SLOTU;
            #pragma unroll
            for (int xt = 0; xt < 4; ++xt) {
                int x0 = xt * 16;
                int pxoff = (x0 + ln) * PXS + h8;
                float4v acc = {0.f, 0.f, 0.f, 0.f};
                #pragma unroll
                for (int f = 0; f < 5; ++f) {
                    const unsigned short* p = xl + sb[f] + pxoff + dxo[f];
                    short4v lo = *(const short4v*)(p);
                    short4v hi = *(const short4v*)(p + 4);
                    short8 a = __builtin_shufflevector(lo, hi, 0, 1, 2, 3, 4, 5, 6, 7);
                    acc = __builtin_amdgcn_mfma_f32_16x16x32_bf16(a, kf[f], acc, 0, 0, 0);
                }
                // D: col = ln = c0, rows = px = x0 + quad*4 + r
                unsigned short* yp = y + ((size_t)(b * 1024 + g * 16 + ln) * 4096
                                          + yo * 64 + x0 + quad * 4);
                short4v o;
                o[0] = (short)f2bf(acc[0]); o[1] = (short)f2bf(acc[1]);
                o[2] = (short)f2bf(acc[2]); o[3] = (short)f2bf(acc[3]);
                *(short4v*)yp = o;
            }
        }

        if (ld) {                              // cvt + ring write (late)
            unsigned short* dst = xl + ((r0 + sub) % NSLOT) * SLOTU + px4 * PXS + wv * 4;
            #pragma unroll
            for (int p = 0; p < 4; ++p) {
                short4v u;
                u[0] = (short)f2bf(q0[p]); u[1] = (short)f2bf(q1[p]);
                u[2] = (short)f2bf(q2[p]); u[3] = (short)f2bf(q3[p]);
                *(short4v*)(dst + p * PXS) = u;
            }
        }
        __syncthreads();
    }
}

// ---------------------------------------------------------------------------
// mix3: SECOND stage. out[b][c0][pix][j] = bias[j] + sum_g y[b,(g,c0),pix]*Wm[g,j]
// Full-128-B-line bf16 gather on L3-resident y; at its write-roofline (~20us).
// grid = 8b * 62 rows = 496 blocks of 512.
// ---------------------------------------------------------------------------
__global__ __launch_bounds__(512, 2) void mix3_kernel(const unsigned short* __restrict__ y,
                                                      const unsigned short* __restrict__ wmb,
                                                      const float* __restrict__ bias,
                                                      float* __restrict__ out) {
    __shared__ __align__(16) unsigned short yl[64 * 1024];  // 128 KB
    int t    = threadIdx.x;
    int bi   = blockIdx.x;
    int prow = bi % OH;
    int b    = bi / OH;

    // ---- stage y row-tile (64 px x 1024 ch) -> LDS, swizzled ----
    {
        int pq = t & 7, grp = t >> 3;                 // 8 px-octets x 64 groups
        const unsigned short* yb = y + ((size_t)b * 1024 * 4096) + prow * 64 + pq * 8;
        #pragma unroll
        for (int it = 0; it < 4; ++it) {
            int qd = it * 64 + grp;                   // 0..255: gq 0..15, c0 0..15
            int gq = qd & 15, c0 = qd >> 4;
            const unsigned short* yp = yb + (size_t)(gq * 4 * 16 + c0) * 4096;
            short8 v0 = *(const short8*)(yp);
            short8 v1 = *(const short8*)(yp + 16 * 4096);
            short8 v2 = *(const short8*)(yp + 32 * 4096);
            short8 v3 = *(const short8*)(yp + 48 * 4096);
            int chunk = gq >> 1;
            int gof   = (gq & 1) * 4;                 // g&7 base within chunk
            #pragma unroll
            for (int pp = 0; pp < 8; ++pp) {
                int px = pq * 8 + pp;
                int csw = chunk ^ (c0 & 7) ^ (pq & 7);
                short4v u;
                u[0] = v0[pp]; u[1] = v1[pp]; u[2] = v2[pp]; u[3] = v3[pp];
                *(short4v*)(yl + px * 1024 + c0 * 64 + csw * 8 + gof) = u;
            }
        }
    }
    __syncthreads();

    // ---- compute: 8 waves x 8 px ----
    int lane = t & 63, wv = t >> 6;
    int ln = lane & 15, quad = lane >> 4;

    short8 bf[8];
    #pragma unroll
    for (int q8 = 0; q8 < 8; ++q8)
        bf[q8] = *(const short8*)(wmb + (q8 * 64 + lane) * 8);  // [jt*2+kh]

    float4v bv[4];
    #pragma unroll
    for (int jt = 0; jt < 4; ++jt)
        bv[jt] = *(const float4v*)(bias + jt * 16 + quad * 4);

    for (int kk = 0; kk < 8; ++kk) {
        int pl = wv * 8 + kk;                         // px in tile = xout
        const unsigned short* arow = yl + pl * 1024 + ln * 64;
        int sx = (ln & 7) ^ ((pl >> 3) & 7);
        short8 a0 = *(const short8*)(arow + (((0 + quad) ^ sx) * 8));
        short8 a1 = *(const short8*)(arow + (((4 + quad) ^ sx) * 8));
        if (pl < OW) {
            float* ob = out + (((size_t)(b * 16 + ln) * OPIX) + prow * OW + pl) * NJ
                        + quad * 4;
            #pragma unroll
            for (int jt = 0; jt < 4; ++jt) {
                float4v acc = bv[jt];
                acc = __builtin_amdgcn_mfma_f32_16x16x32_bf16(bf[jt * 2 + 0], a0, acc, 0, 0, 0);
                acc = __builtin_amdgcn_mfma_f32_16x16x32_bf16(bf[jt * 2 + 1], a1, acc, 0, 0, 0);
                *(float4v*)(ob + jt * 16) = acc;
            }
        }
    }
}

// ---------------------------------------------------------------------------
// Fallback path (small ws): round-1 kernels, fp32 throughout.
// ---------------------------------------------------------------------------
__global__ __launch_bounds__(64) void wm_kernel(const float* __restrict__ core0,
                                                const float* __restrict__ core1,
                                                const float* __restrict__ core2,
                                                float* __restrict__ Wm) {
    int g = threadIdx.x;
    int i1 = g >> 4, i2 = (g >> 2) & 3, i3 = g & 3;
    for (int j = 0; j < NJ; ++j) {
        int j1 = j >> 4, j2 = (j >> 2) & 3, j3 = j & 3;
        float s = 0.f;
        #pragma unroll
        for (int r1 = 0; r1 < 8; ++r1) {
            float a = core0[(i1 * 4 + j1) * 8 + r1];
            float t = 0.f;
            #pragma unroll
            for (int r2 = 0; r2 < 8; ++r2) {
                t += core1[((r1 * 4 + i2) * 4 + j2) * 8 + r2] *
                     core2[(r2 * 4 + i3) * 4 + j3];
            }
            s += a * t;
        }
        Wm[g * NJ + j] = s;
    }
}

__global__ __launch_bounds__(256) void fused_fallback(const float* __restrict__ x,
                                                      const float* __restrict__ K,
                                                      const float* __restrict__ Wm,
                                                      const float* __restrict__ bias,
                                                      float* __restrict__ out) {
    __shared__ float wlds[NG * NJ];
    __shared__ float klds[NCI * 9];
    int blk  = blockIdx.x;
    int pblk = blk & 15;
    int c0   = (blk >> 4) & 15;
    int b    = blk >> 8;
    for (int i = threadIdx.x; i < NG * NJ; i += 256) wlds[i] = Wm[i];
    for (int i = threadIdx.x; i < NCI * 9; i += 256) klds[i] = K[c0 * NCI * 9 + i];
    __syncthreads();

    int pix = pblk * 256 + threadIdx.x;
    if (pix >= OPIX) return;
    int yy = pix / OW;
    int xx = pix % OW;

    float acc[NJ];
    #pragma unroll
    for (int j = 0; j < NJ; ++j) acc[j] = 0.f;

    for (int g = 0; g < NG; ++g) {
        float c = 0.f;
        const float* xb = x + ((size_t)(b * NG + g) * NCI) * IPIX;
        for (int ci = 0; ci < NCI; ++ci) {
            #pragma unroll
            for (int dy = 0; dy < 3; ++dy) {
                #pragma unroll
                for (int dx = 0; dx < 3; ++dx) {
                    c += xb[ci * IPIX + (yy + dy) * IW + (xx + dx)] *
                         klds[ci * 9 + dy * 3 + dx];
                }
            }
        }
        const float4* wp = (const float4*)&wlds[g * NJ];
        #pragma unroll
        for (int j4 = 0; j4 < 16; ++j4) {
            float4 w = wp[j4];
            acc[j4 * 4 + 0] += w.x * c;
            acc[j4 * 4 + 1] += w.y * c;
            acc[j4 * 4 + 2] += w.z * c;
            acc[j4 * 4 + 3] += w.w * c;
        }
    }
    #pragma unroll
    for (int j = 0; j < NJ; ++j) {
        out[(((size_t)(b * NC0 + c0) * OPIX) + pix) * NJ + j] = acc[j] + bias[j];
    }
}

extern "C" void kernel_launch(void* const* d_in, const int* in_sizes, int n_in,
                              void* d_out, int out_size, void* d_ws, size_t ws_size,
                              hipStream_t stream) {
    const float* x     = (const float*)d_in[0];
    const float* K     = (const float*)d_in[1];
    const float* core0 = (const float*)d_in[2];
    const float* core1 = (const float*)d_in[3];
    const float* core2 = (const float*)d_in[4];
    const float* bias  = (const float*)d_in[5];
    float* out = (float*)d_out;

    const size_t z_off   = 16384;
    const size_t z_bytes = (size_t)NB * 1024 * 4096 * sizeof(unsigned short);  // 67.1 MB

    if (ws_size >= z_off + z_bytes + 256) {
        unsigned short* wmb = (unsigned short*)d_ws;                    // 8 KB
        unsigned short* kb  = (unsigned short*)((char*)d_ws + 8192);    // 5 KB
        unsigned short* y   = (unsigned short*)((char*)d_ws + z_off);
        prep_kernel<<<9, 64, 0, stream>>>(K, core0, core1, core2, wmb, kb);
        conv_roll_kernel<<<NB * NG * 4, 256, 0, stream>>>(x, kb, y);
        mix3_kernel<<<NB * OH, 512, 0, stream>>>(y, wmb, bias, out);
    } else {
        float* Wm = (float*)d_ws;
        wm_kernel<<<1, 64, 0, stream>>>(core0, core1, core2, Wm);
        fused_fallback<<<NB * NC0 * 16, 256, 0, stream>>>(x, K, Wm, bias, out);
    }
}

// Round 13
// 96.913 us; speedup vs baseline: 1.0147x; 1.0093x over previous
//
#include <hip/hip_runtime.h>
#include <hip/hip_bf16.h>

// Problem constants
#define NB    8      // batch
#define NG    64     // c_inp groups (g)
#define NCI   16     // conv in channels (ci)
#define NC0   16     // conv out channels (c0)
#define NJ    64     // c_out (j)
#define IH    64
#define IW    64
#define OH    62
#define OW    62
#define IPIX  4096   // 64*64
#define OPIX  3844   // 62*62

typedef __attribute__((ext_vector_type(8))) short  short8;
typedef __attribute__((ext_vector_type(4))) short  short4v;
typedef __attribute__((ext_vector_type(4))) float  float4v;

__device__ __forceinline__ unsigned short f2bf(float f) {
    unsigned int u = __builtin_bit_cast(unsigned int, f);
    unsigned int r = (u + 0x7fffu + ((u >> 16) & 1u)) >> 16;
    return (unsigned short)r;
}

// ---------------------------------------------------------------------------
// prep: blocks 0..7 build Wm fragments (bf16) (jt = bi>>1, kh = bi&1)
//       block 8 builds conv K-fragments kb (K padded to 160 contraction, bf16)
// Fragment convention (16x16x32 bf16): free index = lane&15, k = (lane>>4)*8+i.
// ---------------------------------------------------------------------------
__global__ __launch_bounds__(64) void prep_kernel(const float* __restrict__ K,
                                                  const float* __restrict__ c0_,
                                                  const float* __restrict__ c1_,
                                                  const float* __restrict__ c2_,
                                                  unsigned short* __restrict__ wmb,
                                                  unsigned short* __restrict__ kb) {
    int bi = blockIdx.x;
    int l  = threadIdx.x;
    if (bi < 8) {
        int jt = bi >> 1, kh = bi & 1;
        int j = jt * 16 + (l & 15);
        int j1 = j >> 4, j2 = (j >> 2) & 3, j3 = j & 3;
        for (int i = 0; i < 8; ++i) {
            int g = kh * 32 + (l >> 4) * 8 + i;
            int i1 = g >> 4, i2 = (g >> 2) & 3, i3 = g & 3;
            float s = 0.f;
            #pragma unroll
            for (int r1 = 0; r1 < 8; ++r1) {
                float a = c0_[(i1 * 4 + j1) * 8 + r1];
                float t = 0.f;
                #pragma unroll
                for (int r2 = 0; r2 < 8; ++r2) {
                    t += c1_[((r1 * 4 + i2) * 4 + j2) * 8 + r2] *
                         c2_[(r2 * 4 + i3) * 4 + j3];
                }
                s += a * t;
            }
            wmb[(bi * 64 + l) * 8 + i] = f2bf(s);
        }
    } else {
        int c0i = l & 15, q = l >> 4;
        for (int f = 0; f < 5; ++f) {
            int tap = f * 2 + (q >> 1);  // 0..9; 9 = zero pad
            for (int i = 0; i < 8; ++i) {
                int ci = (q & 1) * 8 + i;
                float v = (tap < 9) ? K[(c0i * 16 + ci) * 9 + tap] : 0.f;
                kb[(f * 64 + l) * 8 + i] = f2bf(v);
            }
        }
    }
}

// ---------------------------------------------------------------------------
// conv_roll (R13): rolling ring + DEPTH-8 per-wave load pipeline (T4).
// y[b][g*16+c0][yo*64+xo] (bf16) = sum_{ci,tap} K[c0,ci,tap]*x[b,g*16+ci,..]
//
// R12 post-mortem: x-read rate ~1.9 TB/s == ~52 lines in flight per CU ==
// 4 loads/wave x ~13 waves (schedule drains vmcnt each chunk). R13 keeps
// TWO register chunks (A/B rotation) so 8 loads stay outstanding across
// every compute phase; writes drain only their own chunk (compiler emits
// counted vmcnt). Ring = 14 slots (37 KB) -> 4 blocks/CU, 16 waves.
// Liveness (mod 14, barrier-separated): it reads rows {4it..4it+5}, writes
// {4it+8..4it+11} -- disjoint; slot reuse only >=1 barrier after retire.
// Staging values, MFMA order, f2bf points unchanged -> identical numerics.
// grid = 8*64*4 bands = 2048 blocks of 256 (4 waves).
// ---------------------------------------------------------------------------
#define PXS   20         // ushorts per px slot (40 B; slots 16..19 = pad)
#define SLOTU 1320       // 66 * PXS ushorts per row-slot
#define NSLOT 14

__global__ __launch_bounds__(256, 4) void conv_roll_kernel(const float* __restrict__ x,
                                                           const unsigned short* __restrict__ kb,
                                                           unsigned short* __restrict__ y) {
    __shared__ __align__(16) unsigned short xl[NSLOT * SLOTU];  // 36960 B
    int t = threadIdx.x, lane = t & 63, wv = t >> 6;
    int split = blockIdx.x & 3;
    int g = (blockIdx.x >> 2) & 63;
    int b = blockIdx.x >> 8;
    int y0 = split * 16;
    int ln = lane & 15, quad = lane >> 4;
    int sub = lane >> 4;             // staging: row within 4-row chunk
    int px4 = (lane & 15) * 4;       // staging: px quad base

    const float* xg = x + (size_t)(b * 1024 + g * 16) * IPIX;
    const float* cch = xg + (size_t)(wv * 4) * IPIX + px4;   // this wave's ci-quad

    // conv fragments + tap geometry
    short8 kf[5]; int dyf[5], dxo[5];
    #pragma unroll
    for (int f = 0; f < 5; ++f) {
        kf[f] = *(const short8*)(kb + (f * 64 + lane) * 8);
        int tap = f * 2 + (quad >> 1);
        if (tap > 8) tap = 8;        // pad chunk: kb is zero there
        dyf[f] = tap / 3;
        dxo[f] = (tap % 3) * PXS;
    }
    int h8 = (quad & 1) * 8;

    // zero-pad px 64,65 in all ring slots (stay zero forever)
    for (int e = t; e < NSLOT * 32; e += 256) {
        int s = e >> 5, rem = e & 31;          // px(2) x ci(16)
        xl[s * SLOTU + (64 + (rem >> 4)) * PXS + (rem & 15)] = 0;
    }

#define LOADCH(r0v, Q)                                                          \
    {   int rr = (r0v) + sub; if (rr > 63) rr = 63;                             \
        const float* a_ = cch + (size_t)rr * 64;                                \
        Q##0 = *(const float4v*)(a_);                                           \
        Q##1 = *(const float4v*)(a_ + IPIX);                                    \
        Q##2 = *(const float4v*)(a_ + 2 * IPIX);                                \
        Q##3 = *(const float4v*)(a_ + 3 * IPIX); }

#define WRITECH(r0v, Q)                                                         \
    {   unsigned short* dst = xl + (((r0v) + sub) % NSLOT) * SLOTU              \
                              + px4 * PXS + wv * 4;                             \
        _Pragma("unroll")                                                       \
        for (int p = 0; p < 4; ++p) {                                           \
            short4v u;                                                          \
            u[0] = (short)f2bf(Q##0[p]); u[1] = (short)f2bf(Q##1[p]);           \
            u[2] = (short)f2bf(Q##2[p]); u[3] = (short)f2bf(Q##3[p]);           \
            *(short4v*)(dst + p * PXS) = u; } }

#define COMPUTE(yov)                                                            \
    {   int yo = (yov);                                                         \
        if (yo < OH) {                                                          \
            int sb[5];                                                          \
            _Pragma("unroll")                                                   \
            for (int f = 0; f < 5; ++f) sb[f] = ((yo + dyf[f]) % NSLOT) * SLOTU;\
            _Pragma("unroll")                                                   \
            for (int xt = 0; xt < 4; ++xt) {                                    \
                int x0 = xt * 16;                                               \
                int pxoff = (x0 + ln) * PXS + h8;                               \
                float4v acc = {0.f, 0.f, 0.f, 0.f};                             \
                _Pragma("unroll")                                               \
                for (int f = 0; f < 5; ++f) {                                   \
                    const unsigned short* p_ = xl + sb[f] + pxoff + dxo[f];     \
                    short4v lo = *(const short4v*)(p_);                         \
                    short4v hi = *(const short4v*)(p_ + 4);                     \
                    short8 a_ = __builtin_shufflevector(lo, hi,                 \
                                    0, 1, 2, 3, 4, 5, 6, 7);                    \
                    acc = __builtin_amdgcn_mfma_f32_16x16x32_bf16(a_, kf[f],    \
                                                                  acc, 0, 0, 0);\
                }                                                               \
                unsigned short* yp = y + ((size_t)(b * 1024 + g * 16 + ln)      \
                                          * 4096 + yo * 64 + x0 + quad * 4);    \
                short4v o;                                                      \
                o[0] = (short)f2bf(acc[0]); o[1] = (short)f2bf(acc[1]);         \
                o[2] = (short)f2bf(acc[2]); o[3] = (short)f2bf(acc[3]);         \
                *(short4v*)yp = o; } } }

    float4v A0, A1, A2, A3, B0, B1, B2, B3;

    // ---- prologue: rows y0..y0+7 staged; ch2 (rows +8..11) left in flight ----
    LOADCH(y0 + 0, A)
    LOADCH(y0 + 4, B)
    WRITECH(y0 + 0, A)
    WRITECH(y0 + 4, B)
    LOADCH(y0 + 8, A)                       // A = ch2, in flight
    __syncthreads();

    // it0: issue ch3 -> compute -> write ch2 (drains A only; B stays out)
    LOADCH(y0 + 12, B)
    COMPUTE(y0 + 0 + wv)
    WRITECH(y0 + 8, A)
    __syncthreads();

    // it1: issue ch4 -> compute -> write ch3
    LOADCH(y0 + 16, A)
    COMPUTE(y0 + 4 + wv)
    WRITECH(y0 + 12, B)
    __syncthreads();

    // it2: compute -> write ch4
    COMPUTE(y0 + 8 + wv)
    WRITECH(y0 + 16, A)
    __syncthreads();

    // it3: compute (no staging left)
    COMPUTE(y0 + 12 + wv)

#undef LOADCH
#undef WRITECH
#undef COMPUTE
}

// ---------------------------------------------------------------------------
// mix3: SECOND stage. out[b][c0][pix][j] = bias[j] + sum_g y[b,(g,c0),pix]*Wm[g,j]
// Full-128-B-line bf16 gather on L3-resident y; at its write-roofline (~20us).
// grid = 8b * 62 rows = 496 blocks of 512.
// ---------------------------------------------------------------------------
__global__ __launch_bounds__(512, 2) void mix3_kernel(const unsigned short* __restrict__ y,
                                                      const unsigned short* __restrict__ wmb,
                                                      const float* __restrict__ bias,
                                                      float* __restrict__ out) {
    __shared__ __align__(16) unsigned short yl[64 * 1024];  // 128 KB
    int t    = threadIdx.x;
    int bi   = blockIdx.x;
    int prow = bi % OH;
    int b    = bi / OH;

    // ---- stage y row-tile (64 px x 1024 ch) -> LDS, swizzled ----
    {
        int pq = t & 7, grp = t >> 3;                 // 8 px-octets x 64 groups
        const unsigned short* yb = y + ((size_t)b * 1024 * 4096) + prow * 64 + pq * 8;
        #pragma unroll
        for (int it = 0; it < 4; ++it) {
            int qd = it * 64 + grp;                   // 0..255: gq 0..15, c0 0..15
            int gq = qd & 15, c0 = qd >> 4;
            const unsigned short* yp = yb + (size_t)(gq * 4 * 16 + c0) * 4096;
            short8 v0 = *(const short8*)(yp);
            short8 v1 = *(const short8*)(yp + 16 * 4096);
            short8 v2 = *(const short8*)(yp + 32 * 4096);
            short8 v3 = *(const short8*)(yp + 48 * 4096);
            int chunk = gq >> 1;
            int gof   = (gq & 1) * 4;                 // g&7 base within chunk
            #pragma unroll
            for (int pp = 0; pp < 8; ++pp) {
                int px = pq * 8 + pp;
                int csw = chunk ^ (c0 & 7) ^ (pq & 7);
                short4v u;
                u[0] = v0[pp]; u[1] = v1[pp]; u[2] = v2[pp]; u[3] = v3[pp];
                *(short4v*)(yl + px * 1024 + c0 * 64 + csw * 8 + gof) = u;
            }
        }
    }
    __syncthreads();

    // ---- compute: 8 waves x 8 px ----
    int lane = t & 63, wv = t >> 6;
    int ln = lane & 15, quad = lane >> 4;

    short8 bf[8];
    #pragma unroll
    for (int q8 = 0; q8 < 8; ++q8)
        bf[q8] = *(const short8*)(wmb + (q8 * 64 + lane) * 8);  // [jt*2+kh]

    float4v bv[4];
    #pragma unroll
    for (int jt = 0; jt < 4; ++jt)
        bv[jt] = *(const float4v*)(bias + jt * 16 + quad * 4);

    for (int kk = 0; kk < 8; ++kk) {
        int pl = wv * 8 + kk;                         // px in tile = xout
        const unsigned short* arow = yl + pl * 1024 + ln * 64;
        int sx = (ln & 7) ^ ((pl >> 3) & 7);
        short8 a0 = *(const short8*)(arow + (((0 + quad) ^ sx) * 8));
        short8 a1 = *(const short8*)(arow + (((4 + quad) ^ sx) * 8));
        if (pl < OW) {
            float* ob = out + (((size_t)(b * 16 + ln) * OPIX) + prow * OW + pl) * NJ
                        + quad * 4;
            #pragma unroll
            for (int jt = 0; jt < 4; ++jt) {
                float4v acc = bv[jt];
                acc = __builtin_amdgcn_mfma_f32_16x16x32_bf16(bf[jt * 2 + 0], a0, acc, 0, 0, 0);
                acc = __builtin_amdgcn_mfma_f32_16x16x32_bf16(bf[jt * 2 + 1], a1, acc, 0, 0, 0);
                *(float4v*)(ob + jt * 16) = acc;
            }
        }
    }
}

// ---------------------------------------------------------------------------
// Fallback path (small ws): round-1 kernels, fp32 throughout.
// ---------------------------------------------------------------------------
__global__ __launch_bounds__(64) void wm_kernel(const float* __restrict__ core0,
                                                const float* __restrict__ core1,
                                                const float* __restrict__ core2,
                                                float* __restrict__ Wm) {
    int g = threadIdx.x;
    int i1 = g >> 4, i2 = (g >> 2) & 3, i3 = g & 3;
    for (int j = 0; j < NJ; ++j) {
        int j1 = j >> 4, j2 = (j >> 2) & 3, j3 = j & 3;
        float s = 0.f;
        #pragma unroll
        for (int r1 = 0; r1 < 8; ++r1) {
            float a = core0[(i1 * 4 + j1) * 8 + r1];
            float t = 0.f;
            #pragma unroll
            for (int r2 = 0; r2 < 8; ++r2) {
                t += core1[((r1 * 4 + i2) * 4 + j2) * 8 + r2] *
                     core2[(r2 * 4 + i3) * 4 + j3];
            }
            s += a * t;
        }
        Wm[g * NJ + j] = s;
    }
}

__global__ __launch_bounds__(256) void fused_fallback(const float* __restrict__ x,
                                                      const float* __restrict__ K,
                                                      const float* __restrict__ Wm,
                                                      const float* __restrict__ bias,
                                                      float* __restrict__ out) {
    __shared__ float wlds[NG * NJ];
    __shared__ float klds[NCI * 9];
    int blk  = blockIdx.x;
    int pblk = blk & 15;
    int c0   = (blk >> 4) & 15;
    int b    = blk >> 8;
    for (int i = threadIdx.x; i < NG * NJ; i += 256) wlds[i] = Wm[i];
    for (int i = threadIdx.x; i < NCI * 9; i += 256) klds[i] = K[c0 * NCI * 9 + i];
    __syncthreads();

    int pix = pblk * 256 + threadIdx.x;
    if (pix >= OPIX) return;
    int yy = pix / OW;
    int xx = pix % OW;

    float acc[NJ];
    #pragma unroll
    for (int j = 0; j < NJ; ++j) acc[j] = 0.f;

    for (int g = 0; g < NG; ++g) {
        float c = 0.f;
        const float* xb = x + ((size_t)(b * NG + g) * NCI) * IPIX;
        for (int ci = 0; ci < NCI; ++ci) {
            #pragma unroll
            for (int dy = 0; dy < 3; ++dy) {
                #pragma unroll
                for (int dx = 0; dx < 3; ++dx) {
                    c += xb[ci * IPIX + (yy + dy) * IW + (xx + dx)] *
                         klds[ci * 9 + dy * 3 + dx];
                }
            }
        }
        const float4* wp = (const float4*)&wlds[g * NJ];
        #pragma unroll
        for (int j4 = 0; j4 < 16; ++j4) {
            float4 w = wp[j4];
            acc[j4 * 4 + 0] += w.x * c;
            acc[j4 * 4 + 1] += w.y * c;
            acc[j4 * 4 + 2] += w.z * c;
            acc[j4 * 4 + 3] += w.w * c;
        }
    }
    #pragma unroll
    for (int j = 0; j < NJ; ++j) {
        out[(((size_t)(b * NC0 + c0) * OPIX) + pix) * NJ + j] = acc[j] + bias[j];
    }
}

extern "C" void kernel_launch(void* const* d_in, const int* in_sizes, int n_in,
                              void* d_out, int out_size, void* d_ws, size_t ws_size,
                              hipStream_t stream) {
    const float* x     = (const float*)d_in[0];
    const float* K     = (const float*)d_in[1];
    const float* core0 = (const float*)d_in[2];
    const float* core1 = (const float*)d_in[3];
    const float* core2 = (const float*)d_in[4];
    const float* bias  = (const float*)d_in[5];
    float* out = (float*)d_out;

    const size_t z_off   = 16384;
    const size_t z_bytes = (size_t)NB * 1024 * 4096 * sizeof(unsigned short);  // 67.1 MB

    if (ws_size >= z_off + z_bytes + 256) {
        unsigned short* wmb = (unsigned short*)d_ws;                    // 8 KB
        unsigned short* kb  = (unsigned short*)((char*)d_ws + 8192);    // 5 KB
        unsigned short* y   = (unsigned short*)((char*)d_ws + z_off);
        prep_kernel<<<9, 64, 0, stream>>>(K, core0, core1, core2, wmb, kb);
        conv_roll_kernel<<<NB * NG * 4, 256, 0, stream>>>(x, kb, y);
        mix3_kernel<<<NB * OH, 512, 0, stream>>>(y, wmb, bias, out);
    } else {
        float* Wm = (float*)d_ws;
        wm_kernel<<<1, 64, 0, stream>>>(core0, core1, core2, Wm);
        fused_fallback<<<NB * NC0 * 16, 256, 0, stream>>>(x, K, Wm, bias, out);
    }
}

// Round 14
// 93.811 us; speedup vs baseline: 1.0483x; 1.0331x over previous
//
#include <hip/hip_runtime.h>
#include <hip/hip_bf16.h>

// Problem constants
#define NB    8      // batch
#define NG    64     // c_inp groups (g)
#define NCI   16     // conv in channels (ci)
#define NC0   16     // conv out channels (c0)
#define NJ    64     // c_out (j)
#define IH    64
#define IW    64
#define OH    62
#define OW    62
#define IPIX  4096   // 64*64
#define OPIX  3844   // 62*62

typedef __attribute__((ext_vector_type(8))) short  short8;
typedef __attribute__((ext_vector_type(4))) short  short4v;
typedef __attribute__((ext_vector_type(4))) float  float4v;

__device__ __forceinline__ unsigned short f2bf(float f) {
    unsigned int u = __builtin_bit_cast(unsigned int, f);
    unsigned int r = (u + 0x7fffu + ((u >> 16) & 1u)) >> 16;
    return (unsigned short)r;
}

// ---------------------------------------------------------------------------
// prep: blocks 0..7 build Wm fragments (bf16) (jt = bi>>1, kh = bi&1)
//       block 8 builds conv K-fragments kb (K padded to 160 contraction, bf16)
// Fragment convention (16x16x32 bf16): free index = lane&15, k = (lane>>4)*8+i.
// ---------------------------------------------------------------------------
__global__ __launch_bounds__(64) void prep_kernel(const float* __restrict__ K,
                                                  const float* __restrict__ c0_,
                                                  const float* __restrict__ c1_,
                                                  const float* __restrict__ c2_,
                                                  unsigned short* __restrict__ wmb,
                                                  unsigned short* __restrict__ kb) {
    int bi = blockIdx.x;
    int l  = threadIdx.x;
    if (bi < 8) {
        int jt = bi >> 1, kh = bi & 1;
        int j = jt * 16 + (l & 15);
        int j1 = j >> 4, j2 = (j >> 2) & 3, j3 = j & 3;
        for (int i = 0; i < 8; ++i) {
            int g = kh * 32 + (l >> 4) * 8 + i;
            int i1 = g >> 4, i2 = (g >> 2) & 3, i3 = g & 3;
            float s = 0.f;
            #pragma unroll
            for (int r1 = 0; r1 < 8; ++r1) {
                float a = c0_[(i1 * 4 + j1) * 8 + r1];
                float t = 0.f;
                #pragma unroll
                for (int r2 = 0; r2 < 8; ++r2) {
                    t += c1_[((r1 * 4 + i2) * 4 + j2) * 8 + r2] *
                         c2_[(r2 * 4 + i3) * 4 + j3];
                }
                s += a * t;
            }
            wmb[(bi * 64 + l) * 8 + i] = f2bf(s);
        }
    } else {
        int c0i = l & 15, q = l >> 4;
        for (int f = 0; f < 5; ++f) {
            int tap = f * 2 + (q >> 1);  // 0..9; 9 = zero pad
            for (int i = 0; i < 8; ++i) {
                int ci = (q & 1) * 8 + i;
                float v = (tap < 9) ? K[(c0i * 16 + ci) * 9 + tap] : 0.f;
                kb[(f * 64 + l) * 8 + i] = f2bf(v);
            }
        }
    }
}

// ---------------------------------------------------------------------------
// conv1: FIRST stage (ops commuted: conv before mix, exact by linearity).
// y[b][g*16+c0][yo*64+xo] (bf16, 64-padded rows) =
//     sum_{ci,tap} K[c0,ci,tap] * x[b, g*16+ci, yo+dy, xo+dx]
//
// R14 = REVERT to the R8 configuration (session best, 94.2 us): band of 8
// output rows per block, monolithic stage->barrier->compute, LDS 26.4 KB ->
// 6 blocks/CU. Post-R13 analysis: this config saturates the per-CU memory
// request path (~25 cy/line-requested); all structural alternatives tested
// (sequential streams R9, 2-blk pipeline R10, 5-blk pipeline R12, depth-8
// vmcnt pipeline R13) were null or worse. Concurrency >=6 blocks/CU is the
// only first-order lever, and this config has it.
// LDS tile [s 10][px 66 @PXS=20][ci 16]; fragment = 2x ds_read_b64.
// grid = 8*64*8 = 4096 blocks of 256.
// ---------------------------------------------------------------------------
#define PXS  20          // ushorts per px slot (40 B; slots 16..19 = pad)
#define ROWS 1320        // 66 * PXS ushorts per staged row

__global__ __launch_bounds__(256, 6) void conv1_kernel(const float* __restrict__ x,
                                                       const unsigned short* __restrict__ kb,
                                                       unsigned short* __restrict__ y) {
    __shared__ unsigned short xl[10 * ROWS];  // 26400 B
    int t    = threadIdx.x;
    int bi   = blockIdx.x;
    int band = bi & 7;
    int g    = (bi >> 3) & 63;
    int b    = bi >> 9;
    int y0   = band * 8;

    // ---- stage x rows y0..y0+9 (clamped) -> LDS [s][px][ci] bf16 ----
    {
        int part = t & 15, cig = (t >> 4) & 3, sg = t >> 6;
        const float* xc = x + ((size_t)(b * 1024 + g * 16 + cig * 4) * IPIX) + part * 4;
        #pragma unroll
        for (int k = 0; k < 3; ++k) {
            int s = sg + k * 4;
            if (s < 10) {
                int row = y0 + s; if (row > 63) row = 63;  // only feeds discarded yo>=62
                const float* xr = xc + row * 64;
                float4v v0 = *(const float4v*)(xr);
                float4v v1 = *(const float4v*)(xr + IPIX);
                float4v v2 = *(const float4v*)(xr + 2 * IPIX);
                float4v v3 = *(const float4v*)(xr + 3 * IPIX);
                unsigned short* dst = xl + s * ROWS + (part * 4) * PXS + cig * 4;
                #pragma unroll
                for (int p = 0; p < 4; ++p) {
                    short4v u;
                    u[0] = (short)f2bf(v0[p]); u[1] = (short)f2bf(v1[p]);
                    u[2] = (short)f2bf(v2[p]); u[3] = (short)f2bf(v3[p]);
                    *(short4v*)(dst + p * PXS) = u;
                }
            }
        }
    }
    // zero-pad px 64,65 (read by edge tiles at dx>0)
    for (int e = t; e < 10 * 32; e += 256) {
        int s = e >> 5, rem = e & 31;     // rem = px(2) x ci(16)
        xl[s * ROWS + (64 + (rem >> 4)) * PXS + (rem & 15)] = 0;
    }
    __syncthreads();

    // ---- compute: 4 waves x 8 tiles (16 px x 16 c0 each) ----
    int lane = t & 63, wv = t >> 6;
    int ln = lane & 15, quad = lane >> 4;

    short8 kf[5];
    int off[5];
    #pragma unroll
    for (int f = 0; f < 5; ++f) {
        kf[f] = *(const short8*)(kb + (f * 64 + lane) * 8);
        int tap = f * 2 + (quad >> 1);
        if (tap > 8) tap = 8;             // pad chunk: kb is zero there
        int dy = tap / 3, dx = tap % 3;
        off[f] = dy * ROWS + dx * PXS;
    }
    int h8 = (quad & 1) * 8;

    for (int k = 0; k < 8; ++k) {
        int tid = wv * 8 + k;
        int yr = tid >> 2, x0 = (tid & 3) * 16;
        int yo = y0 + yr;
        const unsigned short* base = xl + yr * ROWS + (x0 + ln) * PXS + h8;
        float4v acc = {0.f, 0.f, 0.f, 0.f};
        #pragma unroll
        for (int f = 0; f < 5; ++f) {
            const unsigned short* p = base + off[f];
            short4v lo = *(const short4v*)(p);
            short4v hi = *(const short4v*)(p + 4);
            short8 a = __builtin_shufflevector(lo, hi, 0, 1, 2, 3, 4, 5, 6, 7);
            acc = __builtin_amdgcn_mfma_f32_16x16x32_bf16(a, kf[f], acc, 0, 0, 0);
        }
        if (yo < OH) {
            // D: col = ln = c0, rows = px = x0 + quad*4 + r
            unsigned short* yp = y + ((size_t)(b * 1024 + g * 16 + ln) * 4096
                                      + yo * 64 + x0 + quad * 4);
            short4v o;
            o[0] = (short)f2bf(acc[0]); o[1] = (short)f2bf(acc[1]);
            o[2] = (short)f2bf(acc[2]); o[3] = (short)f2bf(acc[3]);
            *(short4v*)yp = o;
        }
    }
}

// ---------------------------------------------------------------------------
// mix3: SECOND stage. out[b][c0][pix][j] = bias[j] + sum_g y[b,(g,c0),pix]*Wm[g,j]
// Full-128-B-line bf16 gather on L3-resident y; at its write-roofline (~20us).
// grid = 8b * 62 rows = 496 blocks of 512.
// ---------------------------------------------------------------------------
__global__ __launch_bounds__(512, 2) void mix3_kernel(const unsigned short* __restrict__ y,
                                                      const unsigned short* __restrict__ wmb,
                                                      const float* __restrict__ bias,
                                                      float* __restrict__ out) {
    __shared__ __align__(16) unsigned short yl[64 * 1024];  // 128 KB
    int t    = threadIdx.x;
    int bi   = blockIdx.x;
    int prow = bi % OH;
    int b    = bi / OH;

    // ---- stage y row-tile (64 px x 1024 ch) -> LDS, swizzled ----
    {
        int pq = t & 7, grp = t >> 3;                 // 8 px-octets x 64 groups
        const unsigned short* yb = y + ((size_t)b * 1024 * 4096) + prow * 64 + pq * 8;
        #pragma unroll
        for (int it = 0; it < 4; ++it) {
            int qd = it * 64 + grp;                   // 0..255: gq 0..15, c0 0..15
            int gq = qd & 15, c0 = qd >> 4;
            const unsigned short* yp = yb + (size_t)(gq * 4 * 16 + c0) * 4096;
            short8 v0 = *(const short8*)(yp);
            short8 v1 = *(const short8*)(yp + 16 * 4096);
            short8 v2 = *(const short8*)(yp + 32 * 4096);
            short8 v3 = *(const short8*)(yp + 48 * 4096);
            int chunk = gq >> 1;
            int gof   = (gq & 1) * 4;                 // g&7 base within chunk
            #pragma unroll
            for (int pp = 0; pp < 8; ++pp) {
                int px = pq * 8 + pp;
                int csw = chunk ^ (c0 & 7) ^ (pq & 7);
                short4v u;
                u[0] = v0[pp]; u[1] = v1[pp]; u[2] = v2[pp]; u[3] = v3[pp];
                *(short4v*)(yl + px * 1024 + c0 * 64 + csw * 8 + gof) = u;
            }
        }
    }
    __syncthreads();

    // ---- compute: 8 waves x 8 px ----
    int lane = t & 63, wv = t >> 6;
    int ln = lane & 15, quad = lane >> 4;

    short8 bf[8];
    #pragma unroll
    for (int q8 = 0; q8 < 8; ++q8)
        bf[q8] = *(const short8*)(wmb + (q8 * 64 + lane) * 8);  // [jt*2+kh]

    float4v bv[4];
    #pragma unroll
    for (int jt = 0; jt < 4; ++jt)
        bv[jt] = *(const float4v*)(bias + jt * 16 + quad * 4);

    for (int kk = 0; kk < 8; ++kk) {
        int pl = wv * 8 + kk;                         // px in tile = xout
        const unsigned short* arow = yl + pl * 1024 + ln * 64;
        int sx = (ln & 7) ^ ((pl >> 3) & 7);
        short8 a0 = *(const short8*)(arow + (((0 + quad) ^ sx) * 8));
        short8 a1 = *(const short8*)(arow + (((4 + quad) ^ sx) * 8));
        if (pl < OW) {
            float* ob = out + (((size_t)(b * 16 + ln) * OPIX) + prow * OW + pl) * NJ
                        + quad * 4;
            #pragma unroll
            for (int jt = 0; jt < 4; ++jt) {
                float4v acc = bv[jt];
                acc = __builtin_amdgcn_mfma_f32_16x16x32_bf16(bf[jt * 2 + 0], a0, acc, 0, 0, 0);
                acc = __builtin_amdgcn_mfma_f32_16x16x32_bf16(bf[jt * 2 + 1], a1, acc, 0, 0, 0);
                *(float4v*)(ob + jt * 16) = acc;
            }
        }
    }
}

// ---------------------------------------------------------------------------
// Fallback path (small ws): round-1 kernels, fp32 throughout.
// ---------------------------------------------------------------------------
__global__ __launch_bounds__(64) void wm_kernel(const float* __restrict__ core0,
                                                const float* __restrict__ core1,
                                                const float* __restrict__ core2,
                                                float* __restrict__ Wm) {
    int g = threadIdx.x;
    int i1 = g >> 4, i2 = (g >> 2) & 3, i3 = g & 3;
    for (int j = 0; j < NJ; ++j) {
        int j1 = j >> 4, j2 = (j >> 2) & 3, j3 = j & 3;
        float s = 0.f;
        #pragma unroll
        for (int r1 = 0; r1 < 8; ++r1) {
            float a = core0[(i1 * 4 + j1) * 8 + r1];
            float t = 0.f;
            #pragma unroll
            for (int r2 = 0; r2 < 8; ++r2) {
                t += core1[((r1 * 4 + i2) * 4 + j2) * 8 + r2] *
                     core2[(r2 * 4 + i3) * 4 + j3];
            }
            s += a * t;
        }
        Wm[g * NJ + j] = s;
    }
}

__global__ __launch_bounds__(256) void fused_fallback(const float* __restrict__ x,
                                                      const float* __restrict__ K,
                                                      const float* __restrict__ Wm,
                                                      const float* __restrict__ bias,
                                                      float* __restrict__ out) {
    __shared__ float wlds[NG * NJ];
    __shared__ float klds[NCI * 9];
    int blk  = blockIdx.x;
    int pblk = blk & 15;
    int c0   = (blk >> 4) & 15;
    int b    = blk >> 8;
    for (int i = threadIdx.x; i < NG * NJ; i += 256) wlds[i] = Wm[i];
    for (int i = threadIdx.x; i < NCI * 9; i += 256) klds[i] = K[c0 * NCI * 9 + i];
    __syncthreads();

    int pix = pblk * 256 + threadIdx.x;
    if (pix >= OPIX) return;
    int yy = pix / OW;
    int xx = pix % OW;

    float acc[NJ];
    #pragma unroll
    for (int j = 0; j < NJ; ++j) acc[j] = 0.f;

    for (int g = 0; g < NG; ++g) {
        float c = 0.f;
        const float* xb = x + ((size_t)(b * NG + g) * NCI) * IPIX;
        for (int ci = 0; ci < NCI; ++ci) {
            #pragma unroll
            for (int dy = 0; dy < 3; ++dy) {
                #pragma unroll
                for (int dx = 0; dx < 3; ++dx) {
                    c += xb[ci * IPIX + (yy + dy) * IW + (xx + dx)] *
                         klds[ci * 9 + dy * 3 + dx];
                }
            }
        }
        const float4* wp = (const float4*)&wlds[g * NJ];
        #pragma unroll
        for (int j4 = 0; j4 < 16; ++j4) {
            float4 w = wp[j4];
            acc[j4 * 4 + 0] += w.x * c;
            acc[j4 * 4 + 1] += w.y * c;
            acc[j4 * 4 + 2] += w.z * c;
            acc[j4 * 4 + 3] += w.w * c;
        }
    }
    #pragma unroll
    for (int j = 0; j < NJ; ++j) {
        out[(((size_t)(b * NC0 + c0) * OPIX) + pix) * NJ + j] = acc[j] + bias[j];
    }
}

extern "C" void kernel_launch(void* const* d_in, const int* in_sizes, int n_in,
                              void* d_out, int out_size, void* d_ws, size_t ws_size,
                              hipStream_t stream) {
    const float* x     = (const float*)d_in[0];
    const float* K     = (const float*)d_in[1];
    const float* core0 = (const float*)d_in[2];
    const float* core1 = (const float*)d_in[3];
    const float* core2 = (const float*)d_in[4];
    const float* bias  = (const float*)d_in[5];
    float* out = (float*)d_out;

    const size_t z_off   = 16384;
    const size_t z_bytes = (size_t)NB * 1024 * 4096 * sizeof(unsigned short);  // 67.1 MB

    if (ws_size >= z_off + z_bytes + 256) {
        unsigned short* wmb = (unsigned short*)d_ws;                    // 8 KB
        unsigned short* kb  = (unsigned short*)((char*)d_ws + 8192);    // 5 KB
        unsigned short* y   = (unsigned short*)((char*)d_ws + z_off);
        prep_kernel<<<9, 64, 0, stream>>>(K, core0, core1, core2, wmb, kb);
        conv1_kernel<<<NB * NG * 8, 256, 0, stream>>>(x, kb, y);
        mix3_kernel<<<NB * OH, 512, 0, stream>>>(y, wmb, bias, out);
    } else {
        float* Wm = (float*)d_ws;
        wm_kernel<<<1, 64, 0, stream>>>(core0, core1, core2, Wm);
        fused_fallback<<<NB * NC0 * 16, 256, 0, stream>>>(x, K, Wm, bias, out);
    }
}